// Round 2
// baseline (17781.183 us; speedup 1.0000x reference)
//
#include <hip/hip_runtime.h>
#include <hip/hip_bf16.h>
#include <stdint.h>

typedef __attribute__((ext_vector_type(8))) short short8;
typedef __attribute__((ext_vector_type(4))) short short4v;
typedef __attribute__((ext_vector_type(4))) float f32x4;
using bf16 = __hip_bfloat16;

__device__ __forceinline__ float bfb2f(unsigned short u) {
  union { unsigned u; float f; } x; x.u = ((unsigned)u) << 16; return x.f;
}
__device__ __forceinline__ unsigned short f2bfb(float f) {
  union { float f; unsigned u; } x; x.f = f;
  unsigned r = x.u + 0x7FFFu + ((x.u >> 16) & 1u);
  return (unsigned short)(r >> 16);
}
__device__ __forceinline__ float sigf(float x) { return 1.0f / (1.0f + __expf(-x)); }
__device__ __forceinline__ float tanhf_(float x) {
  x = fminf(fmaxf(x, -15.f), 15.f);
  float e = __expf(2.f * x);
  return 1.f - 2.f / (e + 1.f);
}
__device__ __forceinline__ f32x4 mfma16(short8 a, short8 b, f32x4 c) {
  return __builtin_amdgcn_mfma_f32_16x16x32_bf16(a, b, c, 0, 0, 0);
}
// XOR swizzle on 16B granules: spreads 64B-stride rows across banks (G4/T2)
__device__ __forceinline__ int swz(int b) { return b ^ (((b >> 6) & 7) << 4); }

// global barrier: sense via generation counter; agent-scope release/acquire
__device__ __forceinline__ void gbar(int* cnt, int* gen, int target) {
  __syncthreads();
  if (threadIdx.x == 0) {
    int v = __hip_atomic_fetch_add(cnt, 1, __ATOMIC_ACQ_REL, __HIP_MEMORY_SCOPE_AGENT);
    if (v == 255) {
      __hip_atomic_store(cnt, 0, __ATOMIC_RELAXED, __HIP_MEMORY_SCOPE_AGENT);
      __hip_atomic_fetch_add(gen, 1, __ATOMIC_ACQ_REL, __HIP_MEMORY_SCOPE_AGENT);
    } else {
      while (__hip_atomic_load(gen, __ATOMIC_RELAXED, __HIP_MEMORY_SCOPE_AGENT) < target) {
        __builtin_amdgcn_s_sleep(1);
      }
      __builtin_amdgcn_fence(__ATOMIC_ACQUIRE, "agent");
    }
  }
  __syncthreads();
}

// ---------------- prep / packing kernels ----------------

__global__ void k_pack_apack(const float* __restrict__ w, bf16* __restrict__ out, int CO, int CI) {
  int idx = blockIdx.x * 256 + threadIdx.x;
  int total = 9 * CO * CI;
  if (idx >= total) return;
  int ci = idx % CI; int r = idx / CI; int co = r % CO; int s = r / CO;
  ((unsigned short*)out)[(s * CO + co) * CI + ci] = f2bfb(w[(co * CI + ci) * 9 + s]);
}

__global__ void k_cast(const float* __restrict__ src, bf16* __restrict__ dst, int n) {
  int idx = blockIdx.x * 256 + threadIdx.x;
  if (idx < n) ((unsigned short*)dst)[idx] = f2bfb(src[idx]);
}

__global__ void k_castT512(const float* __restrict__ src, bf16* __restrict__ dst) {
  int idx = blockIdx.x * 256 + threadIdx.x;
  if (idx >= 262144) return;
  int k = idx >> 9, nn = idx & 511;
  ((unsigned short*)dst)[nn * 512 + k] = f2bfb(src[idx]);
}

// Gates B: K=1120 rows = [Wx[:, :80] | 16 zero | Wx[:, 80:592] | Wh], N=2048
__global__ void k_pack_wg(const float* __restrict__ Wx, const float* __restrict__ Wh, bf16* __restrict__ out) {
  int idx = blockIdx.x * 256 + threadIdx.x;
  if (idx >= 2293760) return;
  int kj = idx & 7, jc = (idx >> 3) & 15; int r = idx >> 7;
  int kg = r % 140, jblk = r / 140;
  int k = kg * 8 + kj, j = jblk * 16 + jc;
  float v = 0.f;
  if (k < 80) v = Wx[j * 592 + k];
  else if (k < 96) v = 0.f;
  else if (k < 608) v = Wx[j * 592 + k - 16];
  else v = Wh[j * 512 + k - 608];
  ((unsigned short*)out)[idx] = f2bfb(v);
}
__global__ void k_pack_wo(const float* __restrict__ WO, bf16* __restrict__ out) {
  int idx = blockIdx.x * 256 + threadIdx.x;
  if (idx >= 524288) return;
  int kj = idx & 7, jc = (idx >> 3) & 15; int r = idx >> 7;
  int kg = r % 128, jblk = r / 128;
  int k = kg * 8 + kj, o = jblk * 16 + jc;
  ((unsigned short*)out)[idx] = f2bfb(WO[o * 1024 + k]);
}
__global__ void k_pack_wout(const float* __restrict__ W, bf16* __restrict__ out) {
  int idx = blockIdx.x * 256 + threadIdx.x;
  if (idx >= 262144) return;
  int kj = idx & 7, jc = (idx >> 3) & 15; int r = idx >> 7;
  int kg = r % 64, jblk = r / 64;
  int k = kg * 8 + kj, v = jblk * 16 + jc;
  ((unsigned short*)out)[idx] = (v < 500) ? f2bfb(W[v * 512 + k]) : (unsigned short)0;
}
// Wh_att packed for per-nb K=16 partial MFMA: P[((nb*32+j2)*2+kh)*16+jc][kj]
__global__ void k_pack_whatt(const float* __restrict__ Wha, bf16* __restrict__ out) {
  int idx = blockIdx.x * 256 + threadIdx.x;
  if (idx >= 262144) return;
  int kj = idx & 7, jc = (idx >> 3) & 15, khh = (idx >> 7) & 1, j2 = (idx >> 8) & 31, nb = idx >> 13;
  int k = nb * 16 + khh * 8 + kj, n = j2 * 16 + jc;
  ((unsigned short*)out)[idx] = f2bfb(Wha[k * 512 + n]);
}

// X = [emb(80)+pad16 | O(512)] rows of 608; HC[2][32][1024] zero
__global__ void k_init(bf16* __restrict__ X, bf16* __restrict__ HC, const bf16* __restrict__ Ebf) {
  int idx = blockIdx.x * 256 + threadIdx.x;
  if (idx < 32 * 608) {
    int k = idx % 608;
    unsigned short v = 0;
    if (k < 80) v = ((const unsigned short*)Ebf)[497 * 80 + k];  // start token = vocab-3
    ((unsigned short*)X)[idx] = v;
  }
  if (idx < 65536) ((unsigned short*)HC)[idx] = 0;
}

// ---------------- CNN ----------------

__global__ __launch_bounds__(256) void k_conv1(const float* __restrict__ Xin, const float* __restrict__ w1,
                                               const float* __restrict__ b1, bf16* __restrict__ out) {
  __shared__ float wsm[576];
  __shared__ float xt[4][10];
  const int tid = threadIdx.x;
  const int n = blockIdx.z, y2 = blockIdx.y, xb = blockIdx.x * 4;
  for (int i = tid; i < 576; i += 256) wsm[i] = w1[i];
  if (tid < 40) {
    int rr = tid / 10, cc = tid % 10;
    int gy = 2 * y2 - 1 + rr, gx = 2 * xb - 1 + cc;
    float v = 0.f;
    if (gy >= 0 && gy < 64 && gx >= 0 && gx < 512) v = Xin[n * 32768 + gy * 512 + gx];
    xt[rr][cc] = v;
  }
  __syncthreads();
  const int co = tid & 63, xl = tid >> 6;
  const float bb = b1[co];
  float mx = 0.f;
#pragma unroll
  for (int py = 0; py < 2; ++py)
#pragma unroll
    for (int px = 0; px < 2; ++px) {
      float s = bb;
#pragma unroll
      for (int dy = 0; dy < 3; ++dy)
#pragma unroll
        for (int dx = 0; dx < 3; ++dx)
          s = fmaf(wsm[co * 9 + dy * 3 + dx], xt[py + dy][2 * xl + px + dx], s);
      mx = fmaxf(mx, fmaxf(s, 0.f));
    }
  ((unsigned short*)out)[((n * 34 + y2 + 1) * 258 + (xb + xl) + 1) * 64 + co] = f2bfb(mx);
}

template <int CI, int CO, int H, int W, int MODE>
__global__ __launch_bounds__(256) void k_convgemm(const bf16* __restrict__ inP, const bf16* __restrict__ apack,
                                                  const float* __restrict__ bias, bf16* __restrict__ outp) {
  constexpr int Hp = H + 2, Wp = W + 2;
  __shared__ __align__(16) char As[8192];
  __shared__ __align__(16) char Bs[8192];
  const int tid = threadIdx.x, lane = tid & 63, wv = tid >> 6;
  const int lm = lane & 15, kh = lane >> 4;
  const int wm = wv & 1, wn = wv >> 1;
  const int p0 = blockIdx.x * 128, m0 = blockIdx.y * 128;
  const int n = p0 / (H * W), rem = p0 % (H * W);
  const int y = rem / W, x0 = rem % W;
  const long long pixbase = ((long long)(n * Hp + y) * Wp + x0) * CI;
  f32x4 acc[4][4];
#pragma unroll
  for (int i = 0; i < 4; ++i)
#pragma unroll
    for (int j = 0; j < 4; ++j) acc[i][j] = (f32x4){0.f, 0.f, 0.f, 0.f};
  const int r = tid >> 1, e0 = (tid & 1) * 16;
  const int wb = r * 64 + e0 * 2;
  for (int s = 0; s < 9; ++s) {
    const int dy = s / 3, dx = s % 3;
    const bf16* bsrc = inP + pixbase + (dy * Wp + dx) * CI;
    const bf16* asrc = apack + (s * CO + m0) * CI;
    for (int cc = 0; cc < CI / 32; ++cc) {
      short8 av0 = *(const short8*)(asrc + r * CI + cc * 32 + e0);
      short8 av1 = *(const short8*)(asrc + r * CI + cc * 32 + e0 + 8);
      short8 bv0 = *(const short8*)(bsrc + (long long)r * CI + cc * 32 + e0);
      short8 bv1 = *(const short8*)(bsrc + (long long)r * CI + cc * 32 + e0 + 8);
      __syncthreads();
      *(short8*)(void*)(As + swz(wb)) = av0;
      *(short8*)(void*)(As + swz(wb + 16)) = av1;
      *(short8*)(void*)(Bs + swz(wb)) = bv0;
      *(short8*)(void*)(Bs + swz(wb + 16)) = bv1;
      __syncthreads();
      short8 af[4], bg[4];
#pragma unroll
      for (int i = 0; i < 4; ++i)
        af[i] = *(const short8*)(const void*)(As + swz((wm * 64 + i * 16 + lm) * 64 + kh * 16));
#pragma unroll
      for (int j = 0; j < 4; ++j)
        bg[j] = *(const short8*)(const void*)(Bs + swz((wn * 64 + j * 16 + lm) * 64 + kh * 16));
#pragma unroll
      for (int i = 0; i < 4; ++i)
#pragma unroll
        for (int j = 0; j < 4; ++j) acc[i][j] = mfma16(af[i], bg[j], acc[i][j]);
    }
  }
#pragma unroll
  for (int i = 0; i < 4; ++i) {
    const int co = m0 + wm * 64 + i * 16 + kh * 4;
    float b4[4];
#pragma unroll
    for (int rr = 0; rr < 4; ++rr) b4[rr] = bias[co + rr];
#pragma unroll
    for (int j = 0; j < 4; ++j) {
      const int pix = p0 + wn * 64 + j * 16 + lm;
      short4v pk;
#pragma unroll
      for (int rr = 0; rr < 4; ++rr) {
        float v = fmaxf(acc[i][j][rr] + b4[rr], 0.f);
        pk[rr] = (short)f2bfb(v);
      }
      if constexpr (MODE == 0) {
        *(short4v*)(void*)(outp + (long long)pix * CO + co) = pk;
      } else {
        const int nn = pix / (H * W), r2 = pix % (H * W);
        const int yy = r2 / W, xx = r2 % W;
        *(short4v*)(void*)(outp + ((long long)(nn * Hp + yy + 1) * Wp + xx + 1) * CO + co) = pk;
      }
    }
  }
}

__global__ void k_pool(const bf16* __restrict__ src, bf16* __restrict__ dst,
                       int H, int W, int C, int OHP, int OWP, int pad) {
  const int idx = blockIdx.x * 256 + threadIdx.x;
  const int C8 = C >> 3;
  const int c8 = idx % C8; int tmp = idx / C8;
  const int x2 = tmp % (W >> 1); tmp /= (W >> 1);
  const int y2 = tmp % (H >> 1); const int n = tmp / (H >> 1);
  if (n >= 32) return;
  const long long sbase = ((long long)(n * H + 2 * y2) * W + 2 * x2) * C + c8 * 8;
  short8 a = *(const short8*)(src + sbase);
  short8 b = *(const short8*)(src + sbase + C);
  short8 c = *(const short8*)(src + sbase + (long long)W * C);
  short8 d = *(const short8*)(src + sbase + (long long)W * C + C);
  short8 o;
#pragma unroll
  for (int e = 0; e < 8; ++e) {
    float m = fmaxf(fmaxf(bfb2f((unsigned short)a[e]), bfb2f((unsigned short)b[e])),
                    fmaxf(bfb2f((unsigned short)c[e]), bfb2f((unsigned short)d[e])));
    o[e] = (short)f2bfb(m);
  }
  *(short8*)(void*)(dst + ((long long)(n * OHP + y2 + pad) * OWP + x2 + pad) * C + c8 * 8) = o;
}

__global__ __launch_bounds__(256) void k_gemm_vproj(const bf16* __restrict__ Vb, const bf16* __restrict__ WvT,
                                                    const float* __restrict__ batt, bf16* __restrict__ VP) {
  __shared__ __align__(16) char As[8192];
  __shared__ __align__(16) char Bs[8192];
  const int tid = threadIdx.x, lane = tid & 63, wv = tid >> 6;
  const int lm = lane & 15, kh = lane >> 4;
  const int wm = wv & 1, wn = wv >> 1;
  const int n0 = blockIdx.x * 128, m0 = blockIdx.y * 128;
  f32x4 acc[4][4];
#pragma unroll
  for (int i = 0; i < 4; ++i)
#pragma unroll
    for (int j = 0; j < 4; ++j) acc[i][j] = (f32x4){0.f, 0.f, 0.f, 0.f};
  const int r = tid >> 1, e0 = (tid & 1) * 16;
  const int wb = r * 64 + e0 * 2;
  for (int cc = 0; cc < 16; ++cc) {
    short8 av0 = *(const short8*)(Vb + (m0 + r) * 512 + cc * 32 + e0);
    short8 av1 = *(const short8*)(Vb + (m0 + r) * 512 + cc * 32 + e0 + 8);
    short8 bv0 = *(const short8*)(WvT + (n0 + r) * 512 + cc * 32 + e0);
    short8 bv1 = *(const short8*)(WvT + (n0 + r) * 512 + cc * 32 + e0 + 8);
    __syncthreads();
    *(short8*)(void*)(As + swz(wb)) = av0;
    *(short8*)(void*)(As + swz(wb + 16)) = av1;
    *(short8*)(void*)(Bs + swz(wb)) = bv0;
    *(short8*)(void*)(Bs + swz(wb + 16)) = bv1;
    __syncthreads();
    short8 af[4], bg[4];
#pragma unroll
    for (int i = 0; i < 4; ++i)
      af[i] = *(const short8*)(const void*)(As + swz((wm * 64 + i * 16 + lm) * 64 + kh * 16));
#pragma unroll
    for (int j = 0; j < 4; ++j)
      bg[j] = *(const short8*)(const void*)(Bs + swz((wn * 64 + j * 16 + lm) * 64 + kh * 16));
#pragma unroll
    for (int i = 0; i < 4; ++i)
#pragma unroll
      for (int j = 0; j < 4; ++j) acc[i][j] = mfma16(af[i], bg[j], acc[i][j]);
  }
#pragma unroll
  for (int i = 0; i < 4; ++i)
#pragma unroll
    for (int j = 0; j < 4; ++j) {
      const int nn = n0 + wn * 64 + j * 16 + lm;
      const float ba = batt[nn];
#pragma unroll
      for (int rr = 0; rr < 4; ++rr) {
        const int m = m0 + wm * 64 + i * 16 + kh * 4 + rr;
        ((unsigned short*)VP)[m * 512 + nn] = f2bfb(acc[i][j][rr] + ba);
      }
    }
}

// ---------------- persistent decoder ----------------
// grid = 256 blocks x 256 threads (<=1 block/CU -> co-resident). 4 global bars/step.
// X rows(608): [emb80|pad16|O512]; HC[2][32][1024] bf16: [h(512)|ctx(512)] double-buffered.
__global__ __launch_bounds__(256) void k_decoder(
    bf16* __restrict__ X, bf16* __restrict__ HC, float* __restrict__ partial,
    float* __restrict__ scores, const bf16* __restrict__ WgP, const bf16* __restrict__ WhattP,
    const bf16* __restrict__ WOP, const bf16* __restrict__ WoutP,
    const bf16* __restrict__ Vprj, const bf16* __restrict__ Vbuf,
    const bf16* __restrict__ Ebf, const int* __restrict__ labels,
    const float* __restrict__ bl, const float* __restrict__ beta,
    float* __restrict__ out, int* syncp) {
  const int tid = threadIdx.x, bid = blockIdx.x;
  const int lane = tid & 63, wv = tid >> 6, lm = lane & 15, kh = lane >> 4;
  __shared__ __align__(16) char smem[12288];
  int* cnt = syncp;
  int* gen = syncp + 32;
  int bt = 0;
  float c0 = 0.f, c1 = 0.f;  // persistent LSTM cell state (blocks 0..31)
  const short8 z8 = {0, 0, 0, 0, 0, 0, 0, 0};
  const f32x4 z4 = {0.f, 0.f, 0.f, 0.f};
  unsigned short* Xu = (unsigned short*)X;
  unsigned short* HCu = (unsigned short*)HC;

  for (int t = 0; t < 151; ++t) {
    gbar(cnt, gen, ++bt);
    // ---- phase A: gates GEMM + LSTM (+ hW partials); Q(t-1) on blocks 32..39 ----
    if (bid < 32 && t < 150) {
      const int nb = bid;
      const bf16* hprev = HC + ((t + 1) & 1) * 32768;
      const int jblk = wv * 32 + nb;
      f32x4 acc0 = z4, acc1 = z4;
      for (int kk = 0; kk < 19; ++kk) {
        short8 a0 = *(const short8*)(X + lm * 608 + kk * 32 + kh * 8);
        short8 a1 = *(const short8*)(X + (lm + 16) * 608 + kk * 32 + kh * 8);
        short8 bw = *(const short8*)(WgP + ((jblk * 140 + kk * 4 + kh) * 16 + lm) * 8);
        acc0 = mfma16(a0, bw, acc0); acc1 = mfma16(a1, bw, acc1);
      }
      for (int kk = 19; kk < 35; ++kk) {
        short8 a0 = *(const short8*)(hprev + lm * 1024 + (kk - 19) * 32 + kh * 8);
        short8 a1 = *(const short8*)(hprev + (lm + 16) * 1024 + (kk - 19) * 32 + kh * 8);
        short8 bw = *(const short8*)(WgP + ((jblk * 140 + kk * 4 + kh) * 16 + lm) * 8);
        acc0 = mfma16(a0, bw, acc0); acc1 = mfma16(a1, bw, acc1);
      }
      float* gl = (float*)smem;                               // [4][32][16]
      unsigned short* hsl = (unsigned short*)(smem + 8192);   // [32][16]
      const float bj = bl[wv * 512 + nb * 16 + lm];
#pragma unroll
      for (int rr = 0; rr < 4; ++rr) {
        gl[(wv * 32 + kh * 4 + rr) * 16 + lm] = acc0[rr] + bj;
        gl[(wv * 32 + 16 + kh * 4 + rr) * 16 + lm] = acc1[rr] + bj;
      }
      __syncthreads();
      unsigned short* hcur = HCu + (t & 1) * 32768;
      {
        const int b = tid >> 4, hh = tid & 15;
        float ig = gl[(0 * 32 + b) * 16 + hh], fg = gl[(1 * 32 + b) * 16 + hh];
        float gg = gl[(2 * 32 + b) * 16 + hh], og = gl[(3 * 32 + b) * 16 + hh];
        c0 = sigf(fg) * c0 + sigf(ig) * tanhf_(gg);
        unsigned short hv = f2bfb(sigf(og) * tanhf_(c0));
        hcur[b * 1024 + nb * 16 + hh] = hv; hsl[b * 16 + hh] = hv;
        const int b2 = 16 + b;
        float ig2 = gl[(0 * 32 + b2) * 16 + hh], fg2 = gl[(1 * 32 + b2) * 16 + hh];
        float gg2 = gl[(2 * 32 + b2) * 16 + hh], og2 = gl[(3 * 32 + b2) * 16 + hh];
        c1 = sigf(fg2) * c1 + sigf(ig2) * tanhf_(gg2);
        unsigned short hv2 = f2bfb(sigf(og2) * tanhf_(c1));
        hcur[b2 * 1024 + nb * 16 + hh] = hv2; hsl[b2 * 16 + hh] = hv2;
      }
      __syncthreads();
      // hW partial: h_slice(32x16) @ Whatt_slice(16x512), K padded to 32 with zeros
      short8 a0 = z8, a1 = z8;
      if (kh < 2) {
        a0 = *(const short8*)(hsl + lm * 16 + kh * 8);
        a1 = *(const short8*)(hsl + (16 + lm) * 16 + kh * 8);
      }
      for (int j2 = wv * 8; j2 < wv * 8 + 8; ++j2) {
        short8 bw = z8;
        if (kh < 2) bw = *(const short8*)(WhattP + (((nb * 32 + j2) * 2 + kh) * 16 + lm) * 8);
        f32x4 p0 = mfma16(a0, bw, z4);
        f32x4 p1 = mfma16(a1, bw, z4);
        float* pw = partial + nb * 16384 + j2 * 16 + lm;
#pragma unroll
        for (int rr = 0; rr < 4; ++rr) {
          pw[(kh * 4 + rr) * 512] = p0[rr];
          pw[(16 + kh * 4 + rr) * 512] = p1[rr];
        }
      }
    } else if (bid >= 32 && bid < 40 && t >= 1) {
      const int ntile = (bid - 32) * 4 + wv;
      f32x4 acc0 = z4, acc1 = z4;
      for (int kk = 0; kk < 16; ++kk) {
        short8 a0 = *(const short8*)(X + lm * 608 + 96 + kk * 32 + kh * 8);
        short8 a1 = *(const short8*)(X + (lm + 16) * 608 + 96 + kk * 32 + kh * 8);
        short8 bw = *(const short8*)(WoutP + ((ntile * 64 + kk * 4 + kh) * 16 + lm) * 8);
        acc0 = mfma16(a0, bw, acc0); acc1 = mfma16(a1, bw, acc1);
      }
      const int v = ntile * 16 + lm;
      if (v < 500) {
#pragma unroll
        for (int rr = 0; rr < 4; ++rr) {
          out[((kh * 4 + rr) * 150 + (t - 1)) * 500 + v] = acc0[rr];
          out[((16 + kh * 4 + rr) * 150 + (t - 1)) * 500 + v] = acc1[rr];
        }
      }
    }
    if (t == 150) break;

    gbar(cnt, gen, ++bt);
    // ---- phase B: scores = tanh(Vproj + hW) . beta ; block = (b, 64-l chunk) ----
    {
      const int b = bid >> 3, chunk = bid & 7;
      float* hWl = (float*)smem;               // 512 f32
      float* betal = (float*)(smem + 2048);    // 512 f32
      for (int n = tid; n < 512; n += 256) {
        float s = 0.f;
#pragma unroll 8
        for (int nb = 0; nb < 32; ++nb) s += partial[nb * 16384 + b * 512 + n];
        hWl[n] = s;
        betal[n] = beta[n];
      }
      __syncthreads();
      const int l = chunk * 64 + (tid >> 2), q = tid & 3;
      const bf16* vp = Vprj + (b * 512 + l) * 512 + q * 128;
      float acc = 0.f;
      for (int i = 0; i < 16; ++i) {
        short8 v = *(const short8*)(vp + i * 8);
#pragma unroll
        for (int e = 0; e < 8; ++e) {
          const int n = q * 128 + i * 8 + e;
          acc = fmaf(tanhf_(bfb2f((unsigned short)v[e]) + hWl[n]), betal[n], acc);
        }
      }
      acc += __shfl_xor(acc, 1, 64);
      acc += __shfl_xor(acc, 2, 64);
      if (q == 0) scores[b * 512 + l] = acc;
    }

    gbar(cnt, gen, ++bt);
    // ---- phase C: softmax + ctx ; block = (b, 64-c chunk) ----
    {
      const int b = bid >> 3, cc = bid & 7;
      float* al = (float*)smem;             // 512 f32
      float* prt = (float*)(smem + 2048);   // [4][64]
      float* wr = (float*)(smem + 3072);    // 8 f32
      float s0 = scores[b * 512 + tid], s1 = scores[b * 512 + 256 + tid];
      float m = fmaxf(s0, s1);
#pragma unroll
      for (int off = 32; off >= 1; off >>= 1) m = fmaxf(m, __shfl_xor(m, off, 64));
      if (lane == 0) wr[wv] = m;
      __syncthreads();
      m = fmaxf(fmaxf(wr[0], wr[1]), fmaxf(wr[2], wr[3]));
      float e0 = __expf(s0 - m), e1 = __expf(s1 - m);
      al[tid] = e0; al[tid + 256] = e1;
      float s = e0 + e1;
#pragma unroll
      for (int off = 32; off >= 1; off >>= 1) s += __shfl_xor(s, off, 64);
      if (lane == 0) wr[4 + wv] = s;
      __syncthreads();
      const float rz = 1.f / (wr[4] + wr[5] + wr[6] + wr[7]);
      const int c = cc * 64 + (tid & 63), lq = tid >> 6;
      const unsigned short* vb = (const unsigned short*)Vbuf + (long long)(b * 512 + lq * 128) * 512 + c;
      float acc = 0.f;
      for (int l = 0; l < 128; ++l) acc = fmaf(al[lq * 128 + l], bfb2f(vb[l * 512]), acc);
      prt[lq * 64 + (tid & 63)] = acc;
      __syncthreads();
      if (tid < 64)
        HCu[(t & 1) * 32768 + b * 1024 + 512 + cc * 64 + tid] =
            f2bfb((prt[tid] + prt[64 + tid] + prt[128 + tid] + prt[192 + tid]) * rz);
    }

    gbar(cnt, gen, ++bt);
    // ---- phase D: O = tanh([h|ctx] @ W_O^T) -> X ; emb(t+1) on block 8 ----
    if (bid < 8) {
      const int w = bid * 4 + wv;
      const bf16* hc = HC + (t & 1) * 32768;
      f32x4 acc0 = z4, acc1 = z4;
      for (int kk = 0; kk < 32; ++kk) {
        short8 a0 = *(const short8*)(hc + lm * 1024 + kk * 32 + kh * 8);
        short8 a1 = *(const short8*)(hc + (lm + 16) * 1024 + kk * 32 + kh * 8);
        short8 bw = *(const short8*)(WOP + ((w * 128 + kk * 4 + kh) * 16 + lm) * 8);
        acc0 = mfma16(a0, bw, acc0); acc1 = mfma16(a1, bw, acc1);
      }
      const int o = w * 16 + lm;
#pragma unroll
      for (int rr = 0; rr < 4; ++rr) {
        Xu[(kh * 4 + rr) * 608 + 96 + o] = f2bfb(tanhf_(acc0[rr]));
        Xu[(16 + kh * 4 + rr) * 608 + 96 + o] = f2bfb(tanhf_(acc1[rr]));
      }
    } else if (bid == 8 && t + 1 < 150) {
      for (int idx = tid; idx < 3072; idx += 256) {
        const int b = idx / 96, k = idx % 96;
        unsigned short val = 0;
        if (k < 80) val = ((const unsigned short*)Ebf)[labels[b * 150 + t] * 80 + k];
        Xu[b * 608 + k] = val;
      }
    }
  }
}

// ---------------- launcher ----------------

extern "C" void kernel_launch(void* const* d_in, const int* in_sizes, int n_in,
                              void* d_out, int out_size, void* d_ws, size_t ws_size,
                              hipStream_t stream) {
  (void)in_sizes; (void)n_in; (void)out_size; (void)ws_size;
  const float* Xb = (const float*)d_in[0];
  const int* lab = (const int*)d_in[1];
  const float* w1 = (const float*)d_in[2]; const float* b1 = (const float*)d_in[3];
  const float* w2 = (const float*)d_in[4]; const float* b2 = (const float*)d_in[5];
  const float* w3 = (const float*)d_in[6]; const float* b3 = (const float*)d_in[7];
  const float* w4 = (const float*)d_in[8]; const float* b4 = (const float*)d_in[9];
  const float* E = (const float*)d_in[10];
  const float* Wx = (const float*)d_in[11]; const float* Wh = (const float*)d_in[12];
  const float* blstm = (const float*)d_in[13];
  const float* Wv = (const float*)d_in[14]; const float* Wha = (const float*)d_in[15];
  const float* bat = (const float*)d_in[16]; const float* beta = (const float*)d_in[17];
  const float* WO = (const float*)d_in[18]; const float* Wout = (const float*)d_in[19];
  float* out = (float*)d_out;
  char* ws = (char*)d_ws;

  // workspace layout; decoder state overlays RegB (free once k_pool(pre4) is done)
  constexpr size_t oRegA = 0;                       // in1p | in3p
  constexpr size_t sRegA = 38338560ULL;
  constexpr size_t oRegB = oRegA + sRegA;           // pre2 | pre4 | decoder state
  constexpr size_t oIn2p = oRegB + 67108864ULL;
  constexpr size_t oV    = oIn2p + 19169280ULL;
  constexpr size_t oVprj = oV + 16777216ULL;
  constexpr size_t oAp2  = oVprj + 16777216ULL;
  constexpr size_t oAp3  = oAp2 + 147456ULL;
  constexpr size_t oAp4  = oAp3 + 589824ULL;
  constexpr size_t oWvT  = oAp4 + 2359296ULL;
  constexpr size_t oWgP  = oWvT + 524288ULL;
  constexpr size_t oWOP  = oWgP + 4587520ULL;
  constexpr size_t oWoutP= oWOP + 1048576ULL;
  constexpr size_t oWhatP= oWoutP + 524288ULL;
  constexpr size_t oEbf  = oWhatP + 524288ULL;      // end ~168.6 MB
  // decoder overlay inside RegB:
  constexpr size_t oX    = oRegB;                   // 39,168
  constexpr size_t oHC   = oRegB + 39168ULL;        // 131,072
  constexpr size_t oPart = oRegB + 170240ULL;       // 2,097,152
  constexpr size_t oScr  = oRegB + 2267392ULL;      // 65,536
  constexpr size_t oSync = oRegB + 2332928ULL;      // 256

  bf16* in1p = (bf16*)(ws + oRegA);
  bf16* in3p = (bf16*)(ws + oRegA);
  bf16* pre2 = (bf16*)(ws + oRegB);
  bf16* pre4 = (bf16*)(ws + oRegB);
  bf16* in2p = (bf16*)(ws + oIn2p);
  bf16* Vbuf = (bf16*)(ws + oV);
  bf16* Vprj = (bf16*)(ws + oVprj);
  bf16* Ap2 = (bf16*)(ws + oAp2);
  bf16* Ap3 = (bf16*)(ws + oAp3);
  bf16* Ap4 = (bf16*)(ws + oAp4);
  bf16* WvT = (bf16*)(ws + oWvT);
  bf16* WgP = (bf16*)(ws + oWgP);
  bf16* WOP = (bf16*)(ws + oWOP);
  bf16* WoutP = (bf16*)(ws + oWoutP);
  bf16* WhattP = (bf16*)(ws + oWhatP);
  bf16* Ebf = (bf16*)(ws + oEbf);
  bf16* X = (bf16*)(ws + oX);
  bf16* HC = (bf16*)(ws + oHC);
  float* Part = (float*)(ws + oPart);
  float* Scr = (float*)(ws + oScr);

  // ---- prep ----
  k_pack_apack<<<(9 * 128 * 64 + 255) / 256, 256, 0, stream>>>(w2, Ap2, 128, 64);
  k_pack_apack<<<(9 * 256 * 128 + 255) / 256, 256, 0, stream>>>(w3, Ap3, 256, 128);
  k_pack_apack<<<(9 * 512 * 256 + 255) / 256, 256, 0, stream>>>(w4, Ap4, 512, 256);
  k_castT512<<<1024, 256, 0, stream>>>(Wv, WvT);
  k_cast<<<(40000 + 255) / 256, 256, 0, stream>>>(E, Ebf, 40000);
  k_pack_wg<<<8960, 256, 0, stream>>>(Wx, Wh, WgP);
  k_pack_wo<<<2048, 256, 0, stream>>>(WO, WOP);
  k_pack_wout<<<1024, 256, 0, stream>>>(Wout, WoutP);
  k_pack_whatt<<<1024, 256, 0, stream>>>(Wha, WhattP);

  // ---- CNN ----
  hipMemsetAsync(ws + oRegA, 0, sRegA, stream);
  hipMemsetAsync(ws + oIn2p, 0, 19169280ULL, stream);
  k_conv1<<<dim3(64, 32, 32), 256, 0, stream>>>(Xb, w1, b1, in1p);
  k_convgemm<64, 128, 32, 256, 0><<<dim3(2048, 1), 256, 0, stream>>>(in1p, Ap2, b2, pre2);
  k_pool<<<4096, 256, 0, stream>>>(pre2, in2p, 32, 256, 128, 18, 130, 1);
  hipMemsetAsync(ws + oRegA, 0, sRegA, stream);
  k_convgemm<128, 256, 16, 128, 1><<<dim3(512, 2), 256, 0, stream>>>(in2p, Ap3, b3, in3p);
  k_convgemm<256, 512, 16, 128, 0><<<dim3(512, 4), 256, 0, stream>>>(in3p, Ap4, b4, pre4);
  k_pool<<<4096, 256, 0, stream>>>(pre4, Vbuf, 16, 128, 512, 8, 64, 0);
  k_gemm_vproj<<<dim3(4, 128), 256, 0, stream>>>(Vbuf, WvT, bat, Vprj);

  // ---- decoder (persistent; overlay is free now) ----
  k_init<<<256, 256, 0, stream>>>(X, HC, Ebf);
  hipMemsetAsync(ws + oSync, 0, 256, stream);
  k_decoder<<<256, 256, 0, stream>>>(X, HC, Part, Scr, WgP, WhattP, WOP, WoutP,
                                     Vprj, Vbuf, Ebf, lab, blstm, beta, out,
                                     (int*)(ws + oSync));
}